// Round 12
// baseline (294.427 us; speedup 1.0000x reference)
//
#include <hip/hip_runtime.h>

typedef __attribute__((ext_vector_type(8))) short bf16x8;
typedef __attribute__((ext_vector_type(4))) float f32x4;

__device__ __forceinline__ float bf2f(unsigned short u) {
    union { unsigned u; float f; } x; x.u = (unsigned)u << 16; return x.f;
}
__device__ __forceinline__ unsigned short f2bf(float f) {
    union { float f; unsigned u; } x; x.f = f;
    unsigned r = x.u + 0x7fffu + ((x.u >> 16) & 1u);
    return (unsigned short)(r >> 16);
}

#define GLDS(src, dst) __builtin_amdgcn_global_load_lds( \
    (const __attribute__((address_space(1))) void*)(src), \
    (__attribute__((address_space(3))) void*)(dst), 16, 0, 0)

// ---------------------------------------------------------------------------
// Weight prep (verified R9): 17 logical [256 n][256 k] bf16 matrices, stored
// FRAGMENT-TILED: matrix m at wt + m*65536, [t 0..15][kc 0..7][lane][e]
// with n = t*16 + (lane&15), k = kc*32 + (lane>>4)*8 + e.
// m0=W1(k<128), m1-4=wceff(n<96, conv-folded), m5-8=Wcat(k<96), m9-12=Wf1,
// m13-16=Wf2. bceff [4][256] f32 appended.
// ---------------------------------------------------------------------------
__global__ __launch_bounds__(256) void prep(
    const float* __restrict__ filters,
    const float* __restrict__ Wc1, const float* __restrict__ Wc2, const float* __restrict__ Wc3,
    const float* __restrict__ bc1, const float* __restrict__ bc2, const float* __restrict__ bc3,
    const float* __restrict__ W1, const float* __restrict__ Wcat,
    const float* __restrict__ Wf1, const float* __restrict__ Wf2,
    unsigned short* __restrict__ wt, float* __restrict__ bceff)
{
    int idx = blockIdx.x * 256 + threadIdx.x;
    if (idx < 1114112) {
        const int m    = idx >> 16;          // 0..16
        const int j    = idx & 65535;
        const int t    = j >> 12;
        const int kc   = (j >> 9) & 7;
        const int lane = (j >> 3) & 63;
        const int e    = j & 7;
        const int n = t * 16 + (lane & 15);
        const int k = kc * 32 + (lane >> 4) * 8 + e;
        float v = 0.f;
        if (m == 0) {
            if (k < 128) v = W1[n * 128 + k];
        } else if (m <= 4) {
            if (n < 96) {
                const int it = m - 1, c = n >> 5, jj = n & 31;
                const float* Wc = (c == 0) ? Wc1 : (c == 1) ? Wc2 : Wc3;
                const float* f  = filters + c * 25;
                float acc = 0.f;
                #pragma unroll
                for (int q = 0; q < 25; ++q) {
                    int hh = k + 12 - q;
                    if (hh >= 0 && hh < 256) acc += f[q] * Wc[(it * 32 + jj) * 256 + hh];
                }
                v = acc;
            }
        } else if (m <= 8) {
            const int it = m - 5;
            if (k < 96) v = Wcat[(it * 256 + n) * 96 + k];
        } else if (m <= 12) {
            const int it = m - 9;
            v = Wf1[(it * 256 + n) * 256 + k];
        } else {
            const int it = m - 13;
            v = Wf2[(it * 256 + n) * 256 + k];
        }
        wt[idx] = f2bf(v);
    } else if (idx < 1115136) {
        const int j = idx - 1114112;         // [4][256]
        const int it = j >> 8, n = j & 255;
        float v = 0.f;
        if (n < 96) {
            const int c = n >> 5, jj = n & 31;
            const float* bc = (c == 0) ? bc1 : (c == 1) ? bc2 : bc3;
            v = bc[it * 32 + jj];
        }
        bceff[j] = v;
    }
}

// x f32 [32768][128] -> bf16 row-major
__global__ __launch_bounds__(256) void cvt_x(const float4* __restrict__ x,
                                             ushort4* __restrict__ xb)
{
    int i = blockIdx.x * 256 + threadIdx.x;     // 1048576 total
    float4 v = x[i];
    ushort4 o = { f2bf(v.x), f2bf(v.y), f2bf(v.z), f2bf(v.w) };
    xb[i] = o;
}

// ---------------------------------------------------------------------------
// One GEMM stage: out[M,nstore](bf16,row-major) =
//   LN?( act( A[M,K] @ W^T + bias ) + res ) ; optionally final dot -> outg.
// 512 blocks x 512 threads (8 waves: 2 wm x 4 wn), 64 rows/block,
// 45KB LDS -> 2 blocks/CU, 4 waves/SIMD.
// A row-major bf16 (stride K); W fragment-tiled (prep layout).
// A-staging (FIXED vs R11): lane l holds row (l&15), k-slice (l>>4)*8 —
// matches the MFMA fragment slot GLDS writes at lane*16B.
// acc = mfma(W_frag, act_frag): D col(lane&15)=row m, D row(hi*4+reg)=chan n.
// ---------------------------------------------------------------------------
__global__ __launch_bounds__(512, 4) void gstage(
    const unsigned short* __restrict__ A, int K,
    const unsigned short* __restrict__ Wg,
    const float* __restrict__ bias,
    const unsigned short* __restrict__ res,        // row-major [M][256] or null
    const float* __restrict__ g, const float* __restrict__ be,
    int actmode, const float* __restrict__ alphap,
    int ntw,                                       // n-tiles per wave: 4 (N=256) or 2 (N=128)
    int nstore,                                    // out width/stride: 256 or 128
    unsigned short* __restrict__ out,
    int fdot, const float* __restrict__ Wout, const float* __restrict__ boutp,
    float* __restrict__ outg)
{
    __shared__ __align__(16) unsigned short alds[2][4][512];   // 8KB  A tiles
    __shared__ __align__(16) unsigned short wlds[2][16][512];  // 32KB W tiles
    __shared__ __align__(16) float lnred[512];                 // 2KB
    __shared__ __align__(16) float dotp[256];                  // 1KB

    const int tid  = threadIdx.x;
    const int lane = tid & 63;
    const int wave = tid >> 6;          // 0..7
    const int wm   = wave >> 2;         // 0..1 (32 rows each)
    const int wn   = wave & 3;          // 0..3 (ntw*16 cols each)
    const int l15  = lane & 15;
    const int hi   = lane >> 4;
    const int rowbase = blockIdx.x * 64;
    const int nkc = K >> 5;

    // A tile t (16 rows): lane l -> row t*16+(l&15), k-slice (l>>4)*8 (frag layout)
    #define STAGEA(kc, bf) { if (wave < 4) \
        GLDS(A + (size_t)(rowbase + wave * 16 + (lane & 15)) * K + (kc) * 32 + (lane >> 4) * 8, \
             &alds[bf][wave][0]); }
    #define STAGEW(kc, bf) { \
        GLDS(Wg + (size_t)((wave * 8) + (kc)) * 512 + lane * 8, &wlds[bf][wave][0]); \
        if (ntw == 4) \
            GLDS(Wg + (size_t)(((wave + 8) * 8) + (kc)) * 512 + lane * 8, &wlds[bf][wave + 8][0]); }

    f32x4 acc[2][4];
    #pragma unroll
    for (int mt = 0; mt < 2; ++mt)
        #pragma unroll
        for (int nt = 0; nt < 4; ++nt) acc[mt][nt] = (f32x4){0.f, 0.f, 0.f, 0.f};

    STAGEA(0, 0); STAGEW(0, 0);
    asm volatile("s_waitcnt vmcnt(0) lgkmcnt(0)" ::: "memory");
    __builtin_amdgcn_s_barrier();

    int buf = 0;
    for (int kc = 0; kc < nkc; ++kc) {
        if (kc + 1 < nkc) { STAGEA(kc + 1, buf ^ 1); STAGEW(kc + 1, buf ^ 1); }
        bf16x8 afr[2], wfr[4];
        #pragma unroll
        for (int mt = 0; mt < 2; ++mt)
            afr[mt] = *(const bf16x8*)&alds[buf][wm * 2 + mt][lane * 8];
        #pragma unroll
        for (int nt = 0; nt < 4; ++nt)
            if (nt < ntw)
                wfr[nt] = *(const bf16x8*)&wlds[buf][wn * ntw + nt][lane * 8];
        #pragma unroll
        for (int mt = 0; mt < 2; ++mt)
            #pragma unroll
            for (int nt = 0; nt < 4; ++nt)
                if (nt < ntw)
                    acc[mt][nt] = __builtin_amdgcn_mfma_f32_16x16x32_bf16(
                        wfr[nt], afr[mt], acc[mt][nt], 0, 0, 0);
        asm volatile("s_waitcnt vmcnt(0) lgkmcnt(0)" ::: "memory");
        __builtin_amdgcn_s_barrier();
        buf ^= 1;
    }
    #undef STAGEA
    #undef STAGEW

    // ---- epilogue: bias -> act -> res -> (LN) -> store/dot ----
    const float alpha = alphap ? alphap[0] : 0.1f;
    float vv[2][4][4];
    #pragma unroll
    for (int mt = 0; mt < 2; ++mt) {
        #pragma unroll
        for (int nt = 0; nt < 4; ++nt)
            if (nt < ntw) {
                const int nb = wn * (ntw * 16) + nt * 16 + hi * 4;
                const int row = rowbase + wm * 32 + mt * 16 + l15;
                const float4 bs = *(const float4*)(bias + nb);
                float u0 = acc[mt][nt][0] + bs.x;
                float u1 = acc[mt][nt][1] + bs.y;
                float u2 = acc[mt][nt][2] + bs.z;
                float u3 = acc[mt][nt][3] + bs.w;
                if (actmode) {
                    u0 = u0 >= 0.f ? u0 : alpha * u0;
                    u1 = u1 >= 0.f ? u1 : alpha * u1;
                    u2 = u2 >= 0.f ? u2 : alpha * u2;
                    u3 = u3 >= 0.f ? u3 : alpha * u3;
                }
                if (res) {
                    const ushort4 rv = *(const ushort4*)(res + (size_t)row * 256 + nb);
                    u0 += bf2f(rv.x); u1 += bf2f(rv.y); u2 += bf2f(rv.z); u3 += bf2f(rv.w);
                }
                vv[mt][nt][0] = u0; vv[mt][nt][1] = u1;
                vv[mt][nt][2] = u2; vv[mt][nt][3] = u3;
            }
    }

    float mean[2], rstd[2];
    if (g) {
        #pragma unroll
        for (int mt = 0; mt < 2; ++mt) {
            float sm = 0.f, q = 0.f;
            #pragma unroll
            for (int nt = 0; nt < 4; ++nt) {
                #pragma unroll
                for (int r = 0; r < 4; ++r) { const float v = vv[mt][nt][r]; sm += v; q += v * v; }
            }
            sm += __shfl_xor(sm, 16); sm += __shfl_xor(sm, 32);
            q  += __shfl_xor(q, 16);  q  += __shfl_xor(q, 32);
            if (hi == 0)
                *(float2*)(lnred + (wm * 32 + mt * 16 + l15) * 8 + wn * 2) = make_float2(sm, q);
        }
        __syncthreads();
        #pragma unroll
        for (int mt = 0; mt < 2; ++mt) {
            const int m = wm * 32 + mt * 16 + l15;
            const float4 p0 = *(const float4*)(lnred + m * 8);
            const float4 p1 = *(const float4*)(lnred + m * 8 + 4);
            const float sm = p0.x + p0.z + p1.x + p1.z;
            const float q  = p0.y + p0.w + p1.y + p1.w;
            const float mu = sm * (1.f / 256.f);
            mean[mt] = mu;
            rstd[mt] = rsqrtf(q * (1.f / 256.f) - mu * mu + 1e-5f);
        }
    }

    #pragma unroll
    for (int mt = 0; mt < 2; ++mt) {
        float dp = 0.f;
        #pragma unroll
        for (int nt = 0; nt < 4; ++nt)
            if (nt < ntw) {
                const int nb = wn * (ntw * 16) + nt * 16 + hi * 4;
                const int row = rowbase + wm * 32 + mt * 16 + l15;
                float o0 = vv[mt][nt][0], o1 = vv[mt][nt][1];
                float o2 = vv[mt][nt][2], o3 = vv[mt][nt][3];
                if (g) {
                    const float4 gv = *(const float4*)(g + nb);
                    const float4 bv = *(const float4*)(be + nb);
                    o0 = (o0 - mean[mt]) * rstd[mt] * gv.x + bv.x;
                    o1 = (o1 - mean[mt]) * rstd[mt] * gv.y + bv.y;
                    o2 = (o2 - mean[mt]) * rstd[mt] * gv.z + bv.z;
                    o3 = (o3 - mean[mt]) * rstd[mt] * gv.w + bv.w;
                }
                if (!fdot) {
                    if (nb < nstore) {
                        const ushort4 ov = {f2bf(o0), f2bf(o1), f2bf(o2), f2bf(o3)};
                        *(ushort4*)(out + (size_t)row * nstore + nb) = ov;
                    }
                } else {
                    const float4 wv = *(const float4*)(Wout + nb);
                    dp += o0 * wv.x + o1 * wv.y + o2 * wv.z + o3 * wv.w;
                }
            }
        if (fdot) {
            dp += __shfl_xor(dp, 16); dp += __shfl_xor(dp, 32);
            if (hi == 0) dotp[(wm * 32 + mt * 16 + l15) * 4 + wn] = dp;
        }
    }
    if (fdot) {
        __syncthreads();
        if (tid < 64) {
            const float4 pp = *(const float4*)(dotp + tid * 4);
            outg[rowbase + tid] = pp.x + pp.y + pp.z + pp.w + boutp[0];
        }
    }
}

extern "C" void kernel_launch(void* const* d_in, const int* in_sizes, int n_in,
                              void* d_out, int out_size, void* d_ws, size_t ws_size,
                              hipStream_t stream)
{
    const float* x       = (const float*)d_in[0];
    const float* filters = (const float*)d_in[1];
    const float* W1      = (const float*)d_in[2];
    const float* b1      = (const float*)d_in[3];
    const float* a0      = (const float*)d_in[4];
    const float* g0      = (const float*)d_in[5];
    const float* be0     = (const float*)d_in[6];
    const float* Wc1     = (const float*)d_in[7];
    const float* bc1     = (const float*)d_in[8];
    const float* Wc2     = (const float*)d_in[9];
    const float* bc2     = (const float*)d_in[10];
    const float* Wc3     = (const float*)d_in[11];
    const float* bc3     = (const float*)d_in[12];
    const float* Wcat    = (const float*)d_in[13];
    const float* bcat    = (const float*)d_in[14];
    const float* g1      = (const float*)d_in[15];
    const float* be1     = (const float*)d_in[16];
    const float* Wf1     = (const float*)d_in[17];
    const float* bf1     = (const float*)d_in[18];
    const float* af      = (const float*)d_in[19];
    const float* Wf2     = (const float*)d_in[20];
    const float* bf2     = (const float*)d_in[21];
    const float* g2      = (const float*)d_in[22];
    const float* be2     = (const float*)d_in[23];
    const float* Wout    = (const float*)d_in[24];
    const float* boutp   = (const float*)d_in[25];
    float* outf = (float*)d_out;

    unsigned short* p = (unsigned short*)d_ws;
    unsigned short* wt    = p;                       // 1114112 shorts (2.2MB)
    float*          bceff = (float*)(p + 1114112);   // 1024 f32
    unsigned short* xb    = p + 1116160;             // 32768*128
    unsigned short* act0  = xb + 4194304;            // 32768*256
    unsigned short* act1  = act0 + 8388608;          // 32768*256
    unsigned short* hb    = act1 + 8388608;          // 32768*256
    unsigned short* xcat  = hb + 8388608;            // 32768*128

    prep<<<dim3(4357), dim3(256), 0, stream>>>(
        filters, Wc1, Wc2, Wc3, bc1, bc2, bc3, W1, Wcat, Wf1, Wf2, wt, bceff);
    cvt_x<<<dim3(4096), dim3(256), 0, stream>>>((const float4*)x, (ushort4*)xb);

    dim3 gb(512), tb(512);
    const unsigned short* WT = wt;

    // s0: act0 = ln(prelu(xb @ W1^T + b1, a0), g0, be0)
    gstage<<<gb, tb, 0, stream>>>(xb, 128, WT + 0 * 65536, b1, nullptr, g0, be0,
                                  1, a0, 4, 256, act0, 0, nullptr, nullptr, nullptr);
    for (int it = 0; it < 4; ++it) {
        // xcat = lrelu(act0 @ wceff^T + bceff, 0.1)           N=128
        gstage<<<gb, tb, 0, stream>>>(act0, 256, WT + (size_t)(1 + it) * 65536,
                                      bceff + it * 256, nullptr, nullptr, nullptr,
                                      2, nullptr, 2, 128, xcat, 0, nullptr, nullptr, nullptr);
        // act1 = ln(xcat @ Wcat^T + bcat + act0, g1, be1)     K=128
        gstage<<<gb, tb, 0, stream>>>(xcat, 128, WT + (size_t)(5 + it) * 65536,
                                      bcat + it * 256, act0, g1 + it * 256, be1 + it * 256,
                                      0, nullptr, 4, 256, act1, 0, nullptr, nullptr, nullptr);
        // hb = prelu(act1 @ Wf1^T + bf1, af[it])
        gstage<<<gb, tb, 0, stream>>>(act1, 256, WT + (size_t)(9 + it) * 65536,
                                      bf1 + it * 256, nullptr, nullptr, nullptr,
                                      1, af + it, 4, 256, hb, 0, nullptr, nullptr, nullptr);
        // act0 = ln(hb @ Wf2^T + bf2 + act1, g2, be2); last: fused dot -> outf
        gstage<<<gb, tb, 0, stream>>>(hb, 256, WT + (size_t)(13 + it) * 65536,
                                      bf2 + it * 256, act1, g2 + it * 256, be2 + it * 256,
                                      0, nullptr, 4, 256, act0,
                                      (it == 3) ? 1 : 0, Wout, boutp, outf);
    }
}